// Round 1
// 508.474 us; speedup vs baseline: 1.0032x; 1.0032x over previous
//
#include <hip/hip_runtime.h>
#include <math.h>

// LearnableTD reverse scan: lambda_returns + sum_rewards.
// One block per batch row b; 256 threads x 4 contiguous timesteps.
// Both recurrences are affine with a SHARED multiplier b_t = gamma*(1-d)*lam:
//   sr_t = r_t                                + b_t * sr_{t+1}
//   lr_t = r_t + gamma*(1-d)*(1-lam)*v_{t+1}  + b_t * lr_{t+1}
// Scan structure (v2): per-thread compose (4 steps) -> wave-level suffix scan
// via __shfl_down (6 rounds, no barriers) -> single LDS exchange of the 4
// wave aggregates (48 B, ONE __syncthreads) -> replay. Replaces the previous
// 8-round block Hillis-Steele (16 barriers, 8 dependent LDS round-trips).

#define DF_C 0.99f
#define AL_C 0.95f

__global__ __launch_bounds__(256) void td_scan_kernel(
    const float* __restrict__ values,    // (B, S+1)
    const float* __restrict__ rewards,   // (B, S)
    const float* __restrict__ dones,     // (B, S)
    const float* __restrict__ raw_gamma, // (1,)
    const float* __restrict__ raw_lambd, // (S,)
    float* __restrict__ out,             // [lambda_returns (B,S) | sum_rewards (B,S)]
    int B, int S)
{
    const int b    = blockIdx.x;
    const int tid  = threadIdx.x;
    const int lane = tid & 63;
    const int wv   = tid >> 6;          // wave id, 0..3
    const int t0   = tid * 4;

    // gamma = DF + (1-DF)*(2*sigmoid(rg)-1)   (forward value of _grad_scale)
    const float rg    = raw_gamma[0];
    const float sg    = 1.0f / (1.0f + expf(-rg));
    const float gamma = DF_C + (1.0f - DF_C) * (2.0f * sg - 1.0f);

    // Payload loads: coalesced float4 for rewards/dones (16B aligned: t0 % 4 == 0,
    // row base b*S is a multiple of 4 elements). values row is offset by +1 elem;
    // __builtin_memcpy lets the compiler emit a dwordx4 at 4B alignment.
    const size_t rbase = (size_t)b * S + t0;
    const float4 r4 = *reinterpret_cast<const float4*>(rewards + rbase);
    const float4 d4 = *reinterpret_cast<const float4*>(dones   + rbase);
    float r[4] = {r4.x, r4.y, r4.z, r4.w};
    float d[4] = {d4.x, d4.y, d4.z, d4.w};

    const float* vrow = values + (size_t)b * (S + 1);
    float v[4];
    __builtin_memcpy(v, vrow + t0 + 1, 16);      // v_next at t0..t0+3 (4B-aligned ok)
    const float v_last = vrow[S];                // uniform per block, one line fetch

    float lam[4];
#pragma unroll
    for (int j = 0; j < 4; ++j) {
        const float x = raw_lambd[t0 + j];       // tiny, L2-resident
        const float s = 1.0f / (1.0f + expf(-x));
        lam[j] = AL_C + (1.0f - AL_C) * (2.0f * s - 1.0f);
    }

    // Local composition F_tid = f_{t0} o f_{t0+1} o f_{t0+2} o f_{t0+3}
    // (G o f)(x) = A_G + B_G*a_f + B_G*b_f*x
    float Al = 0.0f, As = 0.0f, Bp = 1.0f;
#pragma unroll
    for (int j = 0; j < 4; ++j) {
        const float g  = gamma * (1.0f - d[j]);
        const float bt = g * lam[j];
        const float at = r[j] + g * (1.0f - lam[j]) * v[j];
        Al = Al + Bp * at;
        As = As + Bp * r[j];
        Bp = Bp * bt;
    }

    // Wave-level inclusive SUFFIX scan (Kogge-Stone over 64 lanes, no barriers):
    // S_l = T_l o T_{l+1} o ... o T_{63}
#pragma unroll
    for (int off = 1; off < 64; off <<= 1) {
        const float al  = __shfl_down(Al, off);
        const float as_ = __shfl_down(As, off);
        const float bb  = __shfl_down(Bp, off);
        if (lane + off < 64) {
            Al = Al + Bp * al;   // self o neighbor
            As = As + Bp * as_;
            Bp = Bp * bb;
        }
    }

    // Exclusive suffix within the wave = inclusive suffix of lane+1 (identity at 63).
    float eAl = __shfl_down(Al, 1);
    float eAs = __shfl_down(As, 1);
    float eB  = __shfl_down(Bp, 1);
    if (lane == 63) { eAl = 0.0f; eAs = 0.0f; eB = 1.0f; }

    // Cross-wave: lane 0 of each wave holds the whole-wave composition W_w.
    __shared__ float wA_l[4], wA_s[4], wB_[4];
    if (lane == 0) { wA_l[wv] = Al; wA_s[wv] = As; wB_[wv] = Bp; }
    __syncthreads();

    // Compose with later waves: E = W_{wv+1} o ... o W_3 (wave-uniform loop).
#pragma unroll
    for (int w2 = 1; w2 < 4; ++w2) {
        if (w2 > wv + 0 && (wv + (4 - w2)) < 4) { /* keep unrollable shape */ }
    }
    for (int w2 = wv + 1; w2 < 4; ++w2) {
        eAl = eAl + eB * wA_l[w2];
        eAs = eAs + eB * wA_s[w2];
        eB  = eB  * wB_[w2];
    }

    // Apply to init: lr_init = values[b][S], sr_init = 0
    float lr = eAl + eB * v_last;
    float sr = eAs;

    // Local replay right-to-left, producing the 4 outputs
    float out_lr[4], out_sr[4];
#pragma unroll
    for (int j = 3; j >= 0; --j) {
        const float g  = gamma * (1.0f - d[j]);
        const float bt = g * lam[j];
        sr = r[j] + bt * sr;
        lr = r[j] + g * (1.0f - lam[j]) * v[j] + bt * lr;
        out_lr[j] = lr;
        out_sr[j] = sr;
    }

    *reinterpret_cast<float4*>(out + rbase) =
        make_float4(out_lr[0], out_lr[1], out_lr[2], out_lr[3]);
    *reinterpret_cast<float4*>(out + (size_t)B * S + rbase) =
        make_float4(out_sr[0], out_sr[1], out_sr[2], out_sr[3]);
}

extern "C" void kernel_launch(void* const* d_in, const int* in_sizes, int n_in,
                              void* d_out, int out_size, void* d_ws, size_t ws_size,
                              hipStream_t stream) {
    const float* values    = (const float*)d_in[0];
    const float* rewards   = (const float*)d_in[1];
    const float* dones     = (const float*)d_in[2];
    const float* raw_gamma = (const float*)d_in[3];
    const float* raw_lambd = (const float*)d_in[4];
    float* out = (float*)d_out;

    const int S = in_sizes[4];       // raw_lambd has length S
    const int B = in_sizes[1] / S;   // rewards is B*S

    dim3 grid(B);
    dim3 block(S / 4);               // 256 threads, 4 timesteps each
    td_scan_kernel<<<grid, block, 0, stream>>>(values, rewards, dones,
                                               raw_gamma, raw_lambd, out, B, S);
}